// Round 19
// baseline (657.526 us; speedup 1.0000x reference)
//
#include <hip/hip_runtime.h>
#include <hip/hip_bf16.h>
#include <cstdint>

#define N_NODES 20000
#define N_EDGES 320000
#define BATCH 8
#define HID 128

// ---------------- workspace layout (bytes) ----------------
static constexpr size_t O_DEG  = 0;
static constexpr size_t O_CUR  = 81920;
static constexpr size_t O_OFF  = 163840;
static constexpr size_t O_DINV = 245760;
static constexpr size_t O_CSR  = 327680;    // u16, padded (<=460000 entries)
static constexpr size_t O_CSRW = 1376256;   // f32, padded
static constexpr size_t O_P32  = 3473408;   // 20000 int (group-32 degree perm)
static constexpr size_t O_HBUF = 3553408;   // 160000*128 f = 81,920,000 B

// chunked h layout: 32 slices, slice (q,b) = [N_NODES][32 floats], contiguous.

__global__ void count_deg(const int* __restrict__ col, int* __restrict__ deg) {
    int e = blockIdx.x * 256 + threadIdx.x;
    if (e < N_EDGES) atomicAdd(&deg[col[e]], 1);
}

__global__ void compute_dinv(const int* __restrict__ deg, float* __restrict__ dinv) {
    int i = blockIdx.x * 256 + threadIdx.x;
    if (i < N_NODES) {
        float d = (float)(deg[i] + 1);   // +1 self loop
        dinv[i] = 1.0f / sqrtf(d);
    }
}

// offsets over PADDED degrees (multiple of 8) -> tail-free aggregate loop.
__global__ __launch_bounds__(1024) void scan_offsets(const int* __restrict__ deg,
                                                     int* __restrict__ off) {
    __shared__ int part[1024];
    const int CH = 20;
    int tid = threadIdx.x;
    int base = tid * CH;
    int s = 0;
    for (int i = 0; i < CH; ++i) {
        int idx = base + i;
        if (idx < N_NODES) s += (deg[idx] + 7) & ~7;
    }
    part[tid] = s;
    __syncthreads();
    for (int d = 1; d < 1024; d <<= 1) {
        int add = 0;
        if (tid >= d) add = part[tid - d];
        __syncthreads();
        part[tid] += add;
        __syncthreads();
    }
    int run = part[tid] - s;
    for (int i = 0; i < CH; ++i) {
        int idx = base + i;
        if (idx < N_NODES) {
            off[idx] = run;
            run += (deg[idx] + 7) & ~7;
        }
    }
    if (tid == 1023) off[N_NODES] = part[1023];
}

// u16 src + precomputed f32 weight (short gather chain: csr -> gather).
__global__ void fill_csr(const int* __restrict__ rowi, const int* __restrict__ coli,
                         const float* __restrict__ dinv, const int* __restrict__ off,
                         int* __restrict__ cursor, uint16_t* __restrict__ csr,
                         float* __restrict__ csrw) {
    int e = blockIdx.x * 256 + threadIdx.x;
    if (e >= N_EDGES) return;
    int r = rowi[e], c = coli[e];
    int pos = atomicAdd(&cursor[c], 1);
    int i = off[c] + pos;
    csr[i] = (uint16_t)r;
    csrw[i] = dinv[r] * dinv[c];
}

// Fill padding slots [deg, pdeg) with (last real src, w=0).
__global__ void pad_csr(const int* __restrict__ deg, const int* __restrict__ off,
                        uint16_t* __restrict__ csr, float* __restrict__ csrw) {
    int n = blockIdx.x * 256 + threadIdx.x;
    if (n >= N_NODES) return;
    int d = deg[n];
    int pd = (d + 7) & ~7;
    int s = off[n];
    uint16_t filler = d > 0 ? csr[s + d - 1] : (uint16_t)n;
    for (int i = d; i < pd; ++i) {
        csr[s + i] = filler;
        csrw[s + i] = 0.0f;
    }
}

// Sort each node's REAL in-edges by src; padding stays at the end.
__global__ __launch_bounds__(64) void sort_adj(const int* __restrict__ degv,
                                               const int* __restrict__ off,
                                               uint16_t* __restrict__ csr,
                                               float* __restrict__ csrw) {
    int n = blockIdx.x;
    int s = off[n];
    int deg = degv[n];
    if (deg <= 1 || deg > 64) return;
    int l = threadIdx.x;
    int my = (l < deg) ? (int)csr[s + l] : 0x7fffffff;
    float mw = (l < deg) ? csrw[s + l] : 0.0f;
    int rank = 0;
    for (int j = 0; j < deg; ++j) {
        int kj = __shfl(my, j);
        rank += (kj < my) || (kj == my && j < l);
    }
    if (l < deg) { csr[s + rank] = (uint16_t)my; csrw[s + rank] = mw; }
}

// Within each group of 32 consecutive nodes, rank-sort by padded degree:
// each wave gets 16 similar-degree nodes; locality window stays 32 nodes.
__global__ __launch_bounds__(64) void build_perm32(const int* __restrict__ deg,
                                                   int* __restrict__ perm) {
    int tid = threadIdx.x;
    int l = tid & 31;
    int grp = blockIdx.x * 2 + (tid >> 5);
    if (grp >= N_NODES / 32) return;
    int n = grp * 32 + l;
    int key = (deg[n] + 7) & ~7;
    int rank = 0;
    for (int j = 0; j < 32; ++j) {
        int kj = __shfl(key, j, 32);
        rank += (kj < key) || (kj == key && j < l);
    }
    perm[grp * 32 + rank] = n;
}

// h0 = concat(x, fixed) @ W_in + b_in, stored CHUNKED: slice(q,b)[n][k&31]
__global__ __launch_bounds__(256) void input_proj(const float* __restrict__ x,
                                                  const float* __restrict__ fixedf,
                                                  const float* __restrict__ W,
                                                  const float* __restrict__ bvec,
                                                  float* __restrict__ h) {
    __shared__ float Ws[16 * HID];
    __shared__ float xs[BATCH * 6];
    __shared__ float fs[10];
    int n = blockIdx.x, tid = threadIdx.x;
    for (int i = tid; i < 16 * HID; i += 256) Ws[i] = W[i];
    if (tid < 48) {
        int b_ = tid / 6, o = tid % 6;
        xs[tid] = x[((size_t)b_ * N_NODES + n) * 6 + o];
    } else if (tid < 58) {
        fs[tid - 48] = fixedf[(size_t)n * 10 + (tid - 48)];
    }
    __syncthreads();
#pragma unroll
    for (int j = 0; j < 4; ++j) {
        int idx = tid + j * 256;
        int bb = idx >> 7, hh = idx & 127;
        float acc = bvec[hh];
#pragma unroll
        for (int k = 0; k < 6; ++k) acc += xs[bb * 6 + k] * Ws[k * HID + hh];
#pragma unroll
        for (int k = 0; k < 10; ++k) acc += fs[k] * Ws[(6 + k) * HID + hh];
        size_t a = ((size_t)((hh >> 5) * 8 + bb) * N_NODES + n) * 32 + (hh & 31);
        h[a] = acc;
    }
}

// XCD-pinned aggregation, CHUNKED layout. 4 lanes/node x 2 float4/lane:
// every gather step issues 2 paired independent 16B loads per lane
// (2x bytes-in-flight at equal VGPR) and wave count halves. 4-edge batches.
__global__ __launch_bounds__(128) void aggregate_xcd(const float* __restrict__ hin,
                                                     const int* __restrict__ off,
                                                     const uint16_t* __restrict__ csr,
                                                     const float* __restrict__ csrw,
                                                     const float* __restrict__ dinv,
                                                     const int* __restrict__ perm,
                                                     float* __restrict__ out,
                                                     int final_scatter) {
    int bid = blockIdx.x;
    int b   = bid & 7;                  // batch == XCD
    int q   = bid / 5000;               // quarter 0..3
    int g   = (bid - q * 5000) >> 3;    // node group 0..624
    int tid = threadIdx.x;              // 0..127
    int nr  = tid >> 2;                 // node rank 0..31 (wave0: 0-15, wave1: 16-31)
    int n   = perm[g * 32 + nr];
    int sub = (tid & 3) * 2;            // float4 pair base: 0,2,4,6
    const size_t SB4 = (size_t)(q * 8 + b) * N_NODES * 8;

    const float4* hp4 = (const float4*)hin;
    float dn = dinv[n];
    float d2 = dn * dn;
    const size_t nb = SB4 + (size_t)n * 8 + sub;
    float4 aL = hp4[nb];
    float4 aH = hp4[nb + 1];
    aL.x *= d2; aL.y *= d2; aL.z *= d2; aL.w *= d2;
    aH.x *= d2; aH.y *= d2; aH.z *= d2; aH.w *= d2;
    float4 bL = make_float4(0.f, 0.f, 0.f, 0.f);
    float4 bH = make_float4(0.f, 0.f, 0.f, 0.f);

    int s = off[n], e = off[n + 1];     // padded range, multiple of 8 (4 | 8)
    for (int p = s; p < e; p += 4) {
        uint2  iv = *(const uint2*)(csr + p);      // 4 u16 srcs (broadcast in group)
        float4 wv = *(const float4*)(csrw + p);
        int s0 = iv.x & 0xffff, s1 = iv.x >> 16;
        int s2 = iv.y & 0xffff, s3 = iv.y >> 16;
        size_t a0 = SB4 + (size_t)s0 * 8 + sub;
        size_t a1 = SB4 + (size_t)s1 * 8 + sub;
        size_t a2 = SB4 + (size_t)s2 * 8 + sub;
        size_t a3 = SB4 + (size_t)s3 * 8 + sub;
        float4 v0L = hp4[a0], v0H = hp4[a0 + 1];
        float4 v1L = hp4[a1], v1H = hp4[a1 + 1];
        float4 v2L = hp4[a2], v2H = hp4[a2 + 1];
        float4 v3L = hp4[a3], v3H = hp4[a3 + 1];
        aL.x += wv.x * v0L.x + wv.y * v1L.x;  bL.x += wv.z * v2L.x + wv.w * v3L.x;
        aL.y += wv.x * v0L.y + wv.y * v1L.y;  bL.y += wv.z * v2L.y + wv.w * v3L.y;
        aL.z += wv.x * v0L.z + wv.y * v1L.z;  bL.z += wv.z * v2L.z + wv.w * v3L.z;
        aL.w += wv.x * v0L.w + wv.y * v1L.w;  bL.w += wv.z * v2L.w + wv.w * v3L.w;
        aH.x += wv.x * v0H.x + wv.y * v1H.x;  bH.x += wv.z * v2H.x + wv.w * v3H.x;
        aH.y += wv.x * v0H.y + wv.y * v1H.y;  bH.y += wv.z * v2H.y + wv.w * v3H.y;
        aH.z += wv.x * v0H.z + wv.y * v1H.z;  bH.z += wv.z * v2H.z + wv.w * v3H.z;
        aH.w += wv.x * v0H.w + wv.y * v1H.w;  bH.w += wv.z * v2H.w + wv.w * v3H.w;
    }
    aL.x += bL.x; aL.y += bL.y; aL.z += bL.z; aL.w += bL.w;
    aH.x += bH.x; aH.y += bH.y; aH.z += bH.z; aH.w += bH.w;

    size_t o4 = final_scatter ? ((size_t)(b * N_NODES + n) * 32 + q * 8 + sub)
                              : (SB4 + (size_t)n * 8 + sub);
    ((float4*)out)[o4] = aL;
    ((float4*)out)[o4 + 1] = aH;
}

// Row transform (round-11 form, empirically fastest), XCD-pinned blocks.
// 128-row tile, 8x8 thread tile, in-place safe per block.
__global__ __launch_bounds__(256) void gemm_bias_relu(const float* __restrict__ in,
                                                      float* __restrict__ outp,
                                                      const float* __restrict__ W,
                                                      const float* __restrict__ bias,
                                                      int dense) {
    __shared__ float As_T[32][132];
    __shared__ float Wls[32][HID];
    int tid = threadIdx.x;
    int rg = tid >> 4;    // rows rg*8 .. rg*8+7
    int cg = tid & 15;    // cols cg*4..+3 and 64+cg*4..+3
    int b  = blockIdx.x & 7;             // batch == XCD
    int n0 = (blockIdx.x >> 3) * 128;    // rows n0..n0+127 (tail clamped)
    float acc[8][8] = {};
    const float4* in4 = (const float4*)in;

    for (int kt = 0; kt < HID; kt += 32) {
        int q = kt >> 5;
        __syncthreads();
#pragma unroll
        for (int i = 0; i < 4; ++i) {
            int f = tid + i * 256;          // 0..1023 over 128 rows x 8 float4
            int row = f >> 3;
            int kk4 = f & 7;
            int n = n0 + row;
            if (n > N_NODES - 1) n = N_NODES - 1;
            size_t rb4 = dense ? (((size_t)b * N_NODES + n) * 32 + q * 8)
                               : (((size_t)(q * 8 + b) * N_NODES + n) * 8);
            float4 v = in4[rb4 + kk4];
            int kk = kk4 << 2;
            As_T[kk + 0][row] = v.x;
            As_T[kk + 1][row] = v.y;
            As_T[kk + 2][row] = v.z;
            As_T[kk + 3][row] = v.w;
        }
#pragma unroll
        for (int i = 0; i < 4; ++i) {
            int f = tid + i * 256;          // 0..1023 over 32 rows x 32 float4
            int row = f >> 5;
            int kk = (f & 31) << 2;
            *(float4*)&Wls[row][kk] = *(const float4*)&W[(size_t)(kt + row) * HID + kk];
        }
        __syncthreads();
#pragma unroll 8
        for (int k = 0; k < 32; ++k) {
            float4 a0 = *(const float4*)&As_T[k][rg * 8];
            float4 a1 = *(const float4*)&As_T[k][rg * 8 + 4];
            float4 w0 = *(const float4*)&Wls[k][cg * 4];
            float4 w1 = *(const float4*)&Wls[k][cg * 4 + 64];
            float av[8] = {a0.x, a0.y, a0.z, a0.w, a1.x, a1.y, a1.z, a1.w};
            float wv[8] = {w0.x, w0.y, w0.z, w0.w, w1.x, w1.y, w1.z, w1.w};
#pragma unroll
            for (int i = 0; i < 8; ++i)
#pragma unroll
                for (int j = 0; j < 8; ++j)
                    acc[i][j] += av[i] * wv[j];
        }
    }

    float4 b0 = *(const float4*)&bias[cg * 4];
    float4 b1 = *(const float4*)&bias[cg * 4 + 64];
    float4* out4 = (float4*)outp;
#pragma unroll
    for (int i = 0; i < 8; ++i) {
        int n = n0 + rg * 8 + i;
        if (n >= N_NODES) break;
        float4 o0, o1;
        o0.x = fmaxf(acc[i][0] + b0.x, 0.0f);
        o0.y = fmaxf(acc[i][1] + b0.y, 0.0f);
        o0.z = fmaxf(acc[i][2] + b0.z, 0.0f);
        o0.w = fmaxf(acc[i][3] + b0.w, 0.0f);
        o1.x = fmaxf(acc[i][4] + b1.x, 0.0f);
        o1.y = fmaxf(acc[i][5] + b1.y, 0.0f);
        o1.z = fmaxf(acc[i][6] + b1.z, 0.0f);
        o1.w = fmaxf(acc[i][7] + b1.w, 0.0f);
        if (dense) {
            size_t r4 = ((size_t)b * N_NODES + n) * 32;
            out4[r4 + cg] = o0;
            out4[r4 + cg + 16] = o1;
        } else {
            int q0 = cg >> 3, f0 = cg & 7;
            out4[((size_t)(q0 * 8 + b) * N_NODES + n) * 8 + f0] = o0;
            out4[((size_t)((q0 + 2) * 8 + b) * N_NODES + n) * 8 + f0] = o1;
        }
    }
}

extern "C" void kernel_launch(void* const* d_in, const int* in_sizes, int n_in,
                              void* d_out, int out_size, void* d_ws, size_t ws_size,
                              hipStream_t stream) {
    const float* x      = (const float*)d_in[0];
    const float* fixedf = (const float*)d_in[1];
    const float* W_in   = (const float*)d_in[2];
    const float* b_in   = (const float*)d_in[3];
    const float* Wg     = (const float*)d_in[4];
    const float* bg     = (const float*)d_in[5];
    const int*   ei     = (const int*)d_in[6];

    const int* rowi = ei;
    const int* coli = ei + N_EDGES;

    char* ws = (char*)d_ws;
    int*      deg    = (int*)(ws + O_DEG);
    int*      cursor = (int*)(ws + O_CUR);
    int*      off    = (int*)(ws + O_OFF);
    float*    dinv   = (float*)(ws + O_DINV);
    uint16_t* csr    = (uint16_t*)(ws + O_CSR);
    float*    csrw   = (float*)(ws + O_CSRW);
    int*      perm   = (int*)(ws + O_P32);
    float*    hA     = (float*)(ws + O_HBUF);   // chunked
    float*    hB     = (float*)d_out;           // chunked intermediate / final dense

    hipMemsetAsync(deg, 0, N_NODES * sizeof(int), stream);
    hipMemsetAsync(cursor, 0, N_NODES * sizeof(int), stream);

    count_deg<<<(N_EDGES + 255) / 256, 256, 0, stream>>>(coli, deg);
    compute_dinv<<<(N_NODES + 255) / 256, 256, 0, stream>>>(deg, dinv);
    scan_offsets<<<1, 1024, 0, stream>>>(deg, off);
    fill_csr<<<(N_EDGES + 255) / 256, 256, 0, stream>>>(rowi, coli, dinv, off, cursor,
                                                        csr, csrw);
    pad_csr<<<(N_NODES + 255) / 256, 256, 0, stream>>>(deg, off, csr, csrw);
    sort_adj<<<N_NODES, 64, 0, stream>>>(deg, off, csr, csrw);
    build_perm32<<<(N_NODES / 32 + 1) / 2, 64, 0, stream>>>(deg, perm);

    input_proj<<<N_NODES, 256, 0, stream>>>(x, fixedf, W_in, b_in, hA);

    const int AB = 4 * 5000;    // 32 (q,b) passes; 128-thread blocks (32 nodes)
    const int GB = 157 * 8;     // XCD-pinned 128-row blocks (tail: 32 rows)

    // L0: hA --agg--> hB (chunked) --gemm in-place (chunked)-->
    aggregate_xcd<<<AB, 128, 0, stream>>>(hA, off, csr, csrw, dinv, perm, hB, 0);
    gemm_bias_relu<<<GB, 256, 0, stream>>>(hB, hB, Wg + 0 * HID * HID, bg + 0 * HID, 0);
    // L1: hB --agg--> hA (chunked) --gemm in-place (chunked)-->
    aggregate_xcd<<<AB, 128, 0, stream>>>(hB, off, csr, csrw, dinv, perm, hA, 0);
    gemm_bias_relu<<<GB, 256, 0, stream>>>(hA, hA, Wg + 1 * HID * HID, bg + 1 * HID, 0);
    // L2: hA --agg(scatter dense [b][n][h])--> d_out --gemm in-place (dense)-->
    aggregate_xcd<<<AB, 128, 0, stream>>>(hA, off, csr, csrw, dinv, perm, (float*)d_out, 1);
    gemm_bias_relu<<<GB, 256, 0, stream>>>((float*)d_out, (float*)d_out,
                                           Wg + 2 * HID * HID, bg + 2 * HID, 1);
}

// Round 20
// 567.526 us; speedup vs baseline: 1.1586x; 1.1586x over previous
//
#include <hip/hip_runtime.h>
#include <hip/hip_bf16.h>
#include <cstdint>

#define N_NODES 20000
#define N_EDGES 320000
#define BATCH 8
#define HID 128

// ---------------- workspace layout (bytes) ----------------
static constexpr size_t O_DEG  = 0;
static constexpr size_t O_CUR  = 81920;
static constexpr size_t O_OFF  = 163840;
static constexpr size_t O_DINV = 245760;
static constexpr size_t O_CSR  = 327680;    // u16, padded (<=460000 entries)
static constexpr size_t O_CSRW = 1376256;   // f32, padded
static constexpr size_t O_P32  = 3473408;   // 20000 int (group-32 degree perm)
static constexpr size_t O_HBUF = 3553408;   // 160000*128 f = 81,920,000 B

// chunked h layout: 32 slices, slice (q,b) = [N_NODES][32 floats], contiguous.

__global__ void count_deg(const int* __restrict__ col, int* __restrict__ deg) {
    int e = blockIdx.x * 256 + threadIdx.x;
    if (e < N_EDGES) atomicAdd(&deg[col[e]], 1);
}

__global__ void compute_dinv(const int* __restrict__ deg, float* __restrict__ dinv) {
    int i = blockIdx.x * 256 + threadIdx.x;
    if (i < N_NODES) {
        float d = (float)(deg[i] + 1);   // +1 self loop
        dinv[i] = 1.0f / sqrtf(d);
    }
}

// offsets over PADDED degrees (multiple of 8) -> tail-free aggregate loop.
__global__ __launch_bounds__(1024) void scan_offsets(const int* __restrict__ deg,
                                                     int* __restrict__ off) {
    __shared__ int part[1024];
    const int CH = 20;
    int tid = threadIdx.x;
    int base = tid * CH;
    int s = 0;
    for (int i = 0; i < CH; ++i) {
        int idx = base + i;
        if (idx < N_NODES) s += (deg[idx] + 7) & ~7;
    }
    part[tid] = s;
    __syncthreads();
    for (int d = 1; d < 1024; d <<= 1) {
        int add = 0;
        if (tid >= d) add = part[tid - d];
        __syncthreads();
        part[tid] += add;
        __syncthreads();
    }
    int run = part[tid] - s;
    for (int i = 0; i < CH; ++i) {
        int idx = base + i;
        if (idx < N_NODES) {
            off[idx] = run;
            run += (deg[idx] + 7) & ~7;
        }
    }
    if (tid == 1023) off[N_NODES] = part[1023];
}

// u16 src + precomputed f32 weight (short gather chain: csr -> gather).
__global__ void fill_csr(const int* __restrict__ rowi, const int* __restrict__ coli,
                         const float* __restrict__ dinv, const int* __restrict__ off,
                         int* __restrict__ cursor, uint16_t* __restrict__ csr,
                         float* __restrict__ csrw) {
    int e = blockIdx.x * 256 + threadIdx.x;
    if (e >= N_EDGES) return;
    int r = rowi[e], c = coli[e];
    int pos = atomicAdd(&cursor[c], 1);
    int i = off[c] + pos;
    csr[i] = (uint16_t)r;
    csrw[i] = dinv[r] * dinv[c];
}

// Fill padding slots [deg, pdeg) with (last real src, w=0).
__global__ void pad_csr(const int* __restrict__ deg, const int* __restrict__ off,
                        uint16_t* __restrict__ csr, float* __restrict__ csrw) {
    int n = blockIdx.x * 256 + threadIdx.x;
    if (n >= N_NODES) return;
    int d = deg[n];
    int pd = (d + 7) & ~7;
    int s = off[n];
    uint16_t filler = d > 0 ? csr[s + d - 1] : (uint16_t)n;
    for (int i = d; i < pd; ++i) {
        csr[s + i] = filler;
        csrw[s + i] = 0.0f;
    }
}

// Sort each node's REAL in-edges by src (also makes summation order — and
// hence the fp output — deterministic despite atomic fill order).
__global__ __launch_bounds__(64) void sort_adj(const int* __restrict__ degv,
                                               const int* __restrict__ off,
                                               uint16_t* __restrict__ csr,
                                               float* __restrict__ csrw) {
    int n = blockIdx.x;
    int s = off[n];
    int deg = degv[n];
    if (deg <= 1 || deg > 64) return;
    int l = threadIdx.x;
    int my = (l < deg) ? (int)csr[s + l] : 0x7fffffff;
    float mw = (l < deg) ? csrw[s + l] : 0.0f;
    int rank = 0;
    for (int j = 0; j < deg; ++j) {
        int kj = __shfl(my, j);
        rank += (kj < my) || (kj == my && j < l);
    }
    if (l < deg) { csr[s + rank] = (uint16_t)my; csrw[s + rank] = mw; }
}

// Within each group of 32 consecutive nodes, rank-sort by padded degree:
// each wave gets 8 similar-degree nodes; locality window stays 32 nodes.
__global__ __launch_bounds__(64) void build_perm32(const int* __restrict__ deg,
                                                   int* __restrict__ perm) {
    int tid = threadIdx.x;
    int l = tid & 31;
    int grp = blockIdx.x * 2 + (tid >> 5);
    if (grp >= N_NODES / 32) return;
    int n = grp * 32 + l;
    int key = (deg[n] + 7) & ~7;
    int rank = 0;
    for (int j = 0; j < 32; ++j) {
        int kj = __shfl(key, j, 32);
        rank += (kj < key) || (kj == key && j < l);
    }
    perm[grp * 32 + rank] = n;
}

// h0 = concat(x, fixed) @ W_in + b_in, stored CHUNKED: slice(q,b)[n][k&31].
// Grid-stride over 10 nodes per block: W_in staged ONCE per block
// (20000 -> 2000 stagings: ~160 MB -> ~16 MB of L2 W traffic).
__global__ __launch_bounds__(256) void input_proj(const float* __restrict__ x,
                                                  const float* __restrict__ fixedf,
                                                  const float* __restrict__ W,
                                                  const float* __restrict__ bvec,
                                                  float* __restrict__ h) {
    __shared__ float Ws[16 * HID];
    __shared__ float xs[BATCH * 6];
    __shared__ float fs[10];
    int tid = threadIdx.x;
    for (int i = tid; i < 16 * HID; i += 256) Ws[i] = W[i];

    float bv[4];
#pragma unroll
    for (int j = 0; j < 4; ++j) bv[j] = bvec[(tid + j * 256) & 127];

    int n0 = blockIdx.x * 10;
    for (int ni = 0; ni < 10; ++ni) {
        int n = n0 + ni;
        __syncthreads();   // Ws ready (first iter); xs/fs consumers done (later)
        if (tid < 48) {
            int b_ = tid / 6, o = tid % 6;
            xs[tid] = x[((size_t)b_ * N_NODES + n) * 6 + o];
        } else if (tid < 58) {
            fs[tid - 48] = fixedf[(size_t)n * 10 + (tid - 48)];
        }
        __syncthreads();
#pragma unroll
        for (int j = 0; j < 4; ++j) {
            int idx = tid + j * 256;
            int bb = idx >> 7, hh = idx & 127;
            float acc = bv[j];
#pragma unroll
            for (int k = 0; k < 6; ++k) acc += xs[bb * 6 + k] * Ws[k * HID + hh];
#pragma unroll
            for (int k = 0; k < 10; ++k) acc += fs[k] * Ws[(6 + k) * HID + hh];
            size_t a = ((size_t)((hh >> 5) * 8 + bb) * N_NODES + n) * 32 + (hh & 31);
            h[a] = acc;
        }
    }
}

// XCD-pinned aggregation, CHUNKED layout, tail-free 8-wide gather batches,
// degree-balanced wave assignment (perm32), precomputed edge weights.
// (round-18 form — best measured: ~90 us/layer, FETCH at compulsory floor)
__global__ __launch_bounds__(256) void aggregate_xcd(const float* __restrict__ hin,
                                                     const int* __restrict__ off,
                                                     const uint16_t* __restrict__ csr,
                                                     const float* __restrict__ csrw,
                                                     const float* __restrict__ dinv,
                                                     const int* __restrict__ perm,
                                                     float* __restrict__ out,
                                                     int final_scatter) {
    int bid = blockIdx.x;
    int b   = bid & 7;                  // batch == XCD
    int q   = bid / 5000;               // quarter 0..3
    int g   = (bid - q * 5000) >> 3;    // node group 0..624
    int tid = threadIdx.x;
    int l = tid & 63;
    int n = perm[g * 32 + ((tid >> 6) << 3) + (l >> 3)];
    int sub = l & 7;                    // float4 within 32-float chunk
    const size_t SB4 = (size_t)(q * 8 + b) * N_NODES * 8;

    const float4* hp4 = (const float4*)hin;
    float dn = dinv[n];
    float d2 = dn * dn;
    float4 acc = hp4[SB4 + (size_t)n * 8 + sub];
    acc.x *= d2; acc.y *= d2; acc.z *= d2; acc.w *= d2;
    float4 acc2 = make_float4(0.f, 0.f, 0.f, 0.f);

    int s = off[n], e = off[n + 1];     // padded range, multiple of 8
    for (int p = s; p < e; p += 8) {
        uint4  iv = *(const uint4*)(csr + p);      // 8 u16 srcs
        float4 wa = *(const float4*)(csrw + p);
        float4 wb = *(const float4*)(csrw + p + 4);
        int s0 = iv.x & 0xffff, s1 = iv.x >> 16;
        int s2 = iv.y & 0xffff, s3 = iv.y >> 16;
        int s4 = iv.z & 0xffff, s5 = iv.z >> 16;
        int s6 = iv.w & 0xffff, s7 = iv.w >> 16;
        float4 v0 = hp4[SB4 + (size_t)s0 * 8 + sub];
        float4 v1 = hp4[SB4 + (size_t)s1 * 8 + sub];
        float4 v2 = hp4[SB4 + (size_t)s2 * 8 + sub];
        float4 v3 = hp4[SB4 + (size_t)s3 * 8 + sub];
        float4 v4 = hp4[SB4 + (size_t)s4 * 8 + sub];
        float4 v5 = hp4[SB4 + (size_t)s5 * 8 + sub];
        float4 v6 = hp4[SB4 + (size_t)s6 * 8 + sub];
        float4 v7 = hp4[SB4 + (size_t)s7 * 8 + sub];
        acc.x  += wa.x * v0.x + wa.y * v1.x + wa.z * v2.x + wa.w * v3.x;
        acc.y  += wa.x * v0.y + wa.y * v1.y + wa.z * v2.y + wa.w * v3.y;
        acc.z  += wa.x * v0.z + wa.y * v1.z + wa.z * v2.z + wa.w * v3.z;
        acc.w  += wa.x * v0.w + wa.y * v1.w + wa.z * v2.w + wa.w * v3.w;
        acc2.x += wb.x * v4.x + wb.y * v5.x + wb.z * v6.x + wb.w * v7.x;
        acc2.y += wb.x * v4.y + wb.y * v5.y + wb.z * v6.y + wb.w * v7.y;
        acc2.z += wb.x * v4.z + wb.y * v5.z + wb.z * v6.z + wb.w * v7.z;
        acc2.w += wb.x * v4.w + wb.y * v5.w + wb.z * v6.w + wb.w * v7.w;
    }
    acc.x += acc2.x; acc.y += acc2.y; acc.z += acc2.z; acc.w += acc2.w;

    size_t o4 = final_scatter ? ((size_t)(b * N_NODES + n) * 32 + q * 8 + sub)
                              : (SB4 + (size_t)n * 8 + sub);
    ((float4*)out)[o4] = acc;
}

// Row transform (round-11 form, empirically fastest), XCD-pinned blocks.
// 128-row tile, 8x8 thread tile, in-place safe per block.
__global__ __launch_bounds__(256) void gemm_bias_relu(const float* __restrict__ in,
                                                      float* __restrict__ outp,
                                                      const float* __restrict__ W,
                                                      const float* __restrict__ bias,
                                                      int dense) {
    __shared__ float As_T[32][132];
    __shared__ float Wls[32][HID];
    int tid = threadIdx.x;
    int rg = tid >> 4;    // rows rg*8 .. rg*8+7
    int cg = tid & 15;    // cols cg*4..+3 and 64+cg*4..+3
    int b  = blockIdx.x & 7;             // batch == XCD
    int n0 = (blockIdx.x >> 3) * 128;    // rows n0..n0+127 (tail clamped)
    float acc[8][8] = {};
    const float4* in4 = (const float4*)in;

    for (int kt = 0; kt < HID; kt += 32) {
        int q = kt >> 5;
        __syncthreads();
#pragma unroll
        for (int i = 0; i < 4; ++i) {
            int f = tid + i * 256;          // 0..1023 over 128 rows x 8 float4
            int row = f >> 3;
            int kk4 = f & 7;
            int n = n0 + row;
            if (n > N_NODES - 1) n = N_NODES - 1;
            size_t rb4 = dense ? (((size_t)b * N_NODES + n) * 32 + q * 8)
                               : (((size_t)(q * 8 + b) * N_NODES + n) * 8);
            float4 v = in4[rb4 + kk4];
            int kk = kk4 << 2;
            As_T[kk + 0][row] = v.x;
            As_T[kk + 1][row] = v.y;
            As_T[kk + 2][row] = v.z;
            As_T[kk + 3][row] = v.w;
        }
#pragma unroll
        for (int i = 0; i < 4; ++i) {
            int f = tid + i * 256;          // 0..1023 over 32 rows x 32 float4
            int row = f >> 5;
            int kk = (f & 31) << 2;
            *(float4*)&Wls[row][kk] = *(const float4*)&W[(size_t)(kt + row) * HID + kk];
        }
        __syncthreads();
#pragma unroll 8
        for (int k = 0; k < 32; ++k) {
            float4 a0 = *(const float4*)&As_T[k][rg * 8];
            float4 a1 = *(const float4*)&As_T[k][rg * 8 + 4];
            float4 w0 = *(const float4*)&Wls[k][cg * 4];
            float4 w1 = *(const float4*)&Wls[k][cg * 4 + 64];
            float av[8] = {a0.x, a0.y, a0.z, a0.w, a1.x, a1.y, a1.z, a1.w};
            float wv[8] = {w0.x, w0.y, w0.z, w0.w, w1.x, w1.y, w1.z, w1.w};
#pragma unroll
            for (int i = 0; i < 8; ++i)
#pragma unroll
                for (int j = 0; j < 8; ++j)
                    acc[i][j] += av[i] * wv[j];
        }
    }

    float4 b0 = *(const float4*)&bias[cg * 4];
    float4 b1 = *(const float4*)&bias[cg * 4 + 64];
    float4* out4 = (float4*)outp;
#pragma unroll
    for (int i = 0; i < 8; ++i) {
        int n = n0 + rg * 8 + i;
        if (n >= N_NODES) break;
        float4 o0, o1;
        o0.x = fmaxf(acc[i][0] + b0.x, 0.0f);
        o0.y = fmaxf(acc[i][1] + b0.y, 0.0f);
        o0.z = fmaxf(acc[i][2] + b0.z, 0.0f);
        o0.w = fmaxf(acc[i][3] + b0.w, 0.0f);
        o1.x = fmaxf(acc[i][4] + b1.x, 0.0f);
        o1.y = fmaxf(acc[i][5] + b1.y, 0.0f);
        o1.z = fmaxf(acc[i][6] + b1.z, 0.0f);
        o1.w = fmaxf(acc[i][7] + b1.w, 0.0f);
        if (dense) {
            size_t r4 = ((size_t)b * N_NODES + n) * 32;
            out4[r4 + cg] = o0;
            out4[r4 + cg + 16] = o1;
        } else {
            int q0 = cg >> 3, f0 = cg & 7;
            out4[((size_t)(q0 * 8 + b) * N_NODES + n) * 8 + f0] = o0;
            out4[((size_t)((q0 + 2) * 8 + b) * N_NODES + n) * 8 + f0] = o1;
        }
    }
}

extern "C" void kernel_launch(void* const* d_in, const int* in_sizes, int n_in,
                              void* d_out, int out_size, void* d_ws, size_t ws_size,
                              hipStream_t stream) {
    const float* x      = (const float*)d_in[0];
    const float* fixedf = (const float*)d_in[1];
    const float* W_in   = (const float*)d_in[2];
    const float* b_in   = (const float*)d_in[3];
    const float* Wg     = (const float*)d_in[4];
    const float* bg     = (const float*)d_in[5];
    const int*   ei     = (const int*)d_in[6];

    const int* rowi = ei;
    const int* coli = ei + N_EDGES;

    char* ws = (char*)d_ws;
    int*      deg    = (int*)(ws + O_DEG);
    int*      cursor = (int*)(ws + O_CUR);
    int*      off    = (int*)(ws + O_OFF);
    float*    dinv   = (float*)(ws + O_DINV);
    uint16_t* csr    = (uint16_t*)(ws + O_CSR);
    float*    csrw   = (float*)(ws + O_CSRW);
    int*      perm   = (int*)(ws + O_P32);
    float*    hA     = (float*)(ws + O_HBUF);   // chunked
    float*    hB     = (float*)d_out;           // chunked intermediate / final dense

    hipMemsetAsync(deg, 0, N_NODES * sizeof(int), stream);
    hipMemsetAsync(cursor, 0, N_NODES * sizeof(int), stream);

    count_deg<<<(N_EDGES + 255) / 256, 256, 0, stream>>>(coli, deg);
    compute_dinv<<<(N_NODES + 255) / 256, 256, 0, stream>>>(deg, dinv);
    scan_offsets<<<1, 1024, 0, stream>>>(deg, off);
    fill_csr<<<(N_EDGES + 255) / 256, 256, 0, stream>>>(rowi, coli, dinv, off, cursor,
                                                        csr, csrw);
    pad_csr<<<(N_NODES + 255) / 256, 256, 0, stream>>>(deg, off, csr, csrw);
    sort_adj<<<N_NODES, 64, 0, stream>>>(deg, off, csr, csrw);
    build_perm32<<<(N_NODES / 32 + 1) / 2, 64, 0, stream>>>(deg, perm);

    input_proj<<<N_NODES / 10, 256, 0, stream>>>(x, fixedf, W_in, b_in, hA);

    const int AB = 4 * 5000;    // 32 (q,b) passes
    const int GB = 157 * 8;     // XCD-pinned 128-row blocks (tail: 32 rows)

    // L0: hA --agg--> hB (chunked) --gemm in-place (chunked)-->
    aggregate_xcd<<<AB, 256, 0, stream>>>(hA, off, csr, csrw, dinv, perm, hB, 0);
    gemm_bias_relu<<<GB, 256, 0, stream>>>(hB, hB, Wg + 0 * HID * HID, bg + 0 * HID, 0);
    // L1: hB --agg--> hA (chunked) --gemm in-place (chunked)-->
    aggregate_xcd<<<AB, 256, 0, stream>>>(hB, off, csr, csrw, dinv, perm, hA, 0);
    gemm_bias_relu<<<GB, 256, 0, stream>>>(hA, hA, Wg + 1 * HID * HID, bg + 1 * HID, 0);
    // L2: hA --agg(scatter dense [b][n][h])--> d_out --gemm in-place (dense)-->
    aggregate_xcd<<<AB, 256, 0, stream>>>(hA, off, csr, csrw, dinv, perm, (float*)d_out, 1);
    gemm_bias_relu<<<GB, 256, 0, stream>>>((float*)d_out, (float*)d_out,
                                           Wg + 2 * HID * HID, bg + 2 * HID, 1);
}